// Round 1
// 94.973 us; speedup vs baseline: 1.0759x; 1.0759x over previous
//
#include <hip/hip_runtime.h>

// ExemplarNoAttention: logits[b,c] = log( sum_{e: label[e]==c} exp(-beta*d2[b,e]) + eps )
// d2[b,e] = ||x_b||^2 + ||e_e||^2 - 2<x_b,e_e>, clamped >= 0; beta = softplus(beta_raw).
//
// Round 10 (from R9 = 102.2 us):
//  (a) SINGLE barrier per stage: the pre-write __syncthreads() was redundant --
//      stage-st writes target buf nb whose last reads finished before the
//      barrier at the end of stage st-1; reads of buf b never alias writes to nb.
//  (b) Block widened to 128 batch cols (grid 8 x 98). Each wave owns TWO 16-col
//      groups that share A-frags, ce, labels and the onehot frag: per-output LDS
//      read traffic, barrier count, and global ex_h redundancy (16x -> 8x) all halve.
//  (c) exp2 prescale: prep folds log2(e) into cb/ce (and main into s2), so the
//      exponent is base-2 and v_exp_f32 is used without the extra v_mul.
//  (d) dead-subtile skip: if all lanes have t <= -25, every p converts to fp16 0
//      (RTE: |v| <= 2^-25 -> 0), so exp/cvt/onehot/MFMA2 are skipped. Bitwise
//      identical result for ANY input; for this data (min d2 ~ 50) nearly all
//      subtiles are dead -> the exp VALU path and 1/3 of MFMAs vanish.
// Flush stays contention-free private partial stores; reduce kernel unchanged.
// Harness floor (~45 us 268 MB poison fill + restores) untouchable.

#define NB      1024
#define NE      50000
#define NE_PAD  50176    // 98 chunks * 512
#define NCHUNK  98
#define KD      64
#define NC      10
#define SROWS   64       // e-rows per stage
#define NSTAGE  8        // 512 / SROWS
#define LROW    72       // padded LDS row stride in halfs (144 B)
#define BCOLS   128      // batch cols per block (2 col-groups of 64 per wave-set)

#define LOG2E   1.4426950408889634f

using half8   = __attribute__((ext_vector_type(8))) _Float16;  // 16x16x32 A/B frag (4 VGPRs)
using half4v  = __attribute__((ext_vector_type(4))) _Float16;  // 16x16x16 A/B frag (2 VGPRs)
using floatx4 = __attribute__((ext_vector_type(4))) float;

__device__ __forceinline__ float softplus_f(float x) {
  return (x > 20.f) ? x : log1pf(__expf(x));
}

__device__ __forceinline__ float exp2_hw(float x) {
#if __has_builtin(__builtin_amdgcn_exp2f)
  return __builtin_amdgcn_exp2f(x);
#else
  return exp2f(x);
#endif
}

// ---------------------------------------------------------------------------
// prep: cast x/exemplars to fp16, cb = -beta*log2e*||x||^2, ce = -beta*log2e*||e||^2,
// padded labels. 16 lanes/row, 16 rows/block, 3200 blocks.
// Pad rows [NE, NE_PAD): ex_h = 0, ce = -1e30 (=> sim exactly 0), label 0.
// ---------------------------------------------------------------------------
__global__ __launch_bounds__(256) void prep_kernel(
    const float* __restrict__ x, const float* __restrict__ ex,
    const int* __restrict__ labels, const float* __restrict__ beta_raw,
    _Float16* __restrict__ ex_h, float* __restrict__ ce,
    _Float16* __restrict__ x_h, float* __restrict__ cb,
    int* __restrict__ lab_pad)
{
  const int tid = threadIdx.x;
  const float nbeta2 = -softplus_f(beta_raw[0]) * LOG2E;  // -beta*log2(e)

  const int row = blockIdx.x * 16 + (tid >> 4);  // 3200*16 = 51200 = NE_PAD + NB
  const int l16 = tid & 15;

  if (row < NE_PAD) {
    float4 v = make_float4(0.f, 0.f, 0.f, 0.f);
    if (row < NE) v = ((const float4*)ex)[row * 16 + l16];
    half4v hv = { (_Float16)v.x, (_Float16)v.y, (_Float16)v.z, (_Float16)v.w };
    *(half4v*)(ex_h + (size_t)row * KD + l16 * 4) = hv;
    float s = v.x*v.x + v.y*v.y + v.z*v.z + v.w*v.w;
    #pragma unroll
    for (int m = 1; m < 16; m <<= 1) s += __shfl_xor(s, m, 64);
    if (l16 == 0) ce[row] = (row < NE) ? (nbeta2 * s) : -1e30f;
    if (l16 == 1) lab_pad[row] = (row < NE) ? labels[row] : 0;
  } else {
    const int rx = row - NE_PAD;  // [0, NB)
    float4 v = ((const float4*)x)[rx * 16 + l16];
    half4v hv = { (_Float16)v.x, (_Float16)v.y, (_Float16)v.z, (_Float16)v.w };
    *(half4v*)(x_h + (size_t)rx * KD + l16 * 4) = hv;
    float s = v.x*v.x + v.y*v.y + v.z*v.z + v.w*v.w;
    #pragma unroll
    for (int m = 1; m < 16; m <<= 1) s += __shfl_xor(s, m, 64);
    if (l16 == 0) cb[rx] = nbeta2 * s;
  }
}

// ---------------------------------------------------------------------------
// main: grid (8 btiles, 98 chunks), block = 4 waves, 128 batch cols per block.
// Wave w owns cols {btile*128 + w*16 .. +16} (group 0) and the same +64 (group 1).
// Per stage (64 e-rows): prefetch next stage global->regs, compute 4 subtiles
// from LDS buf b (shared A-frags feed BOTH col-groups), write regs->buf b^1,
// ONE barrier.
// Subtile: MFMA1 16x16x32 -> d[e][b] per group; t = min(s2*d + cb + ce, 0) in
// log2-domain; if all lanes dead (t<=-25 => fp16(p)==0) skip exp/onehot/MFMA2.
// Else p = exp2(t) fp16, acc_g = MFMA2(onehot, p_g, acc_g)  (onehot shared).
// Flush: plain coalesced stores into part[chunk] -- zero atomics/contention.
// ---------------------------------------------------------------------------
__global__ __launch_bounds__(256) void main_kernel(
    const _Float16* __restrict__ ex_h, const float* __restrict__ ce,
    const _Float16* __restrict__ x_h, const float* __restrict__ cb,
    const int* __restrict__ lab_pad, const float* __restrict__ beta_raw,
    float* __restrict__ part)
{
  __shared__ _Float16 Ah[2][SROWS * LROW];
  __shared__ float    Ce[2][SROWS];
  __shared__ int      Lb[2][SROWS];

  const int tid  = threadIdx.x;
  const int wave = tid >> 6;
  const int lane = tid & 63;
  const int l15  = lane & 15;
  const int quad = lane >> 4;

  const int btile = blockIdx.x;
  const int chunk = blockIdx.y;
  const int e0    = chunk * 512;
  const int bm0   = btile * BCOLS + wave * 16;  // col-group 0
  const int bm1   = bm0 + 64;                   // col-group 1

  const float beta = softplus_f(beta_raw[0]);
  const float s2 = 2.f * beta * LOG2E;

  // x B-frags for both col-groups, loaded once per wave.
  const half8* xr0 = (const half8*)(x_h + (size_t)(bm0 + l15) * KD);
  const half8* xr1 = (const half8*)(x_h + (size_t)(bm1 + l15) * KD);
  const half8 bx00 = xr0[quad];
  const half8 bx01 = xr0[quad + 4];
  const half8 bx10 = xr1[quad];
  const half8 bx11 = xr1[quad + 4];
  const float cb0l = cb[bm0 + l15];
  const float cb1l = cb[bm1 + l15];

  // stage-load lane constants: thread t moves 32 B of row (t>>2), halfs [(t&3)*16..)
  const int srow = tid >> 2;
  const int scol = tid & 3;
  const _Float16* gsrc = ex_h + (size_t)(e0 + srow) * KD + scol * 16;
  const int lofs = srow * LROW + scol * 16;

  // ---- prologue: stage 0 global -> regs -> LDS buf 0 ----
  half8 pr0 = *(const half8*)(gsrc);
  half8 pr1 = *(const half8*)(gsrc + 8);
  float prc = 0.f; int prl = 0;
  if (wave == 0) prc = ce[e0 + lane];
  if (wave == 1) prl = lab_pad[e0 + lane];

  *(half8*)(&Ah[0][lofs])     = pr0;
  *(half8*)(&Ah[0][lofs + 8]) = pr1;
  if (wave == 0) Ce[0][lane] = prc;
  if (wave == 1) Lb[0][lane] = prl;
  __syncthreads();

  floatx4 acc0 = {0.f, 0.f, 0.f, 0.f};
  floatx4 acc1 = {0.f, 0.f, 0.f, 0.f};

  for (int st = 0; st < NSTAGE; ++st) {
    const int b = st & 1;

    // prefetch next stage into registers (vmcnt chain, independent of ds_reads)
    if (st + 1 < NSTAGE) {
      const _Float16* g = gsrc + (size_t)(st + 1) * SROWS * KD;
      pr0 = *(const half8*)(g);
      pr1 = *(const half8*)(g + 8);
      if (wave == 0) prc = ce[e0 + (st + 1) * SROWS + lane];
      if (wave == 1) prl = lab_pad[e0 + (st + 1) * SROWS + lane];
    }

    // compute 4 subtiles of 16 e-rows from LDS buf b
    #pragma unroll
    for (int sub = 0; sub < 4; ++sub) {
      const int abase = (sub * 16 + l15) * LROW + quad * 8;
      const half8 ae0 = *(const half8*)(&Ah[b][abase]);
      const half8 ae1 = *(const half8*)(&Ah[b][abase + 32]);
      const float4 ce4 = *(const float4*)(&Ce[b][sub * 16 + quad * 4]);
      const int4   lb4 = *(const int4*)(&Lb[b][sub * 16 + quad * 4]);

      floatx4 d0 = {0.f, 0.f, 0.f, 0.f};
      floatx4 d1 = {0.f, 0.f, 0.f, 0.f};
      d0 = __builtin_amdgcn_mfma_f32_16x16x32_f16(ae0, bx00, d0, 0, 0, 0);
      d0 = __builtin_amdgcn_mfma_f32_16x16x32_f16(ae1, bx01, d0, 0, 0, 0);
      d1 = __builtin_amdgcn_mfma_f32_16x16x32_f16(ae0, bx10, d1, 0, 0, 0);
      d1 = __builtin_amdgcn_mfma_f32_16x16x32_f16(ae1, bx11, d1, 0, 0, 0);

      const float cef[4] = { ce4.x, ce4.y, ce4.z, ce4.w };
      float t0[4], t1[4];
      #pragma unroll
      for (int r = 0; r < 4; ++r) {
        t0[r] = fminf(fmaf(s2, d0[r], cb0l + cef[r]), 0.f);  // log2-domain
        t1[r] = fminf(fmaf(s2, d1[r], cb1l + cef[r]), 0.f);
      }

      // dead-subtile skip: t <= -25 => fp16(2^t) == 0 exactly (RTE), so the
      // MFMA2 contribution is a provable no-op. Wave-uniform branch.
      const float m0 = fmaxf(fmaxf(t0[0], t0[1]), fmaxf(t0[2], t0[3]));
      const float m1 = fmaxf(fmaxf(t1[0], t1[1]), fmaxf(t1[2], t1[3]));
      if (__any(fmaxf(m0, m1) > -25.f)) {
        half4v oh;
        oh[0] = (lb4.x == l15) ? (_Float16)1.f : (_Float16)0.f;
        oh[1] = (lb4.y == l15) ? (_Float16)1.f : (_Float16)0.f;
        oh[2] = (lb4.z == l15) ? (_Float16)1.f : (_Float16)0.f;
        oh[3] = (lb4.w == l15) ? (_Float16)1.f : (_Float16)0.f;

        half4v p0, p1;
        #pragma unroll
        for (int r = 0; r < 4; ++r) {
          p0[r] = (_Float16)exp2_hw(t0[r]);
          p1[r] = (_Float16)exp2_hw(t1[r]);
        }

        acc0 = __builtin_amdgcn_mfma_f32_16x16x16f16(oh, p0, acc0, 0, 0, 0);
        acc1 = __builtin_amdgcn_mfma_f32_16x16x16f16(oh, p1, acc1, 0, 0, 0);
      }
    }

    // single barrier per stage: writes go to buf b^1, whose last reads ended
    // before the barrier at the end of stage st-1; reads of buf b don't alias.
    if (st + 1 < NSTAGE) {
      const int nb = (st + 1) & 1;
      *(half8*)(&Ah[nb][lofs])     = pr0;
      *(half8*)(&Ah[nb][lofs + 8]) = pr1;
      if (wave == 0) Ce[nb][lane] = prc;
      if (wave == 1) Lb[nb][lane] = prl;
      __syncthreads();
    }
  }

  // Flush: acc holds class_part[c = quad*4+r][b = l15] per col-group. Private
  // per-chunk slice, plain stores, zero contention (each cell written once).
  float* dst = part + (size_t)chunk * (NB * NC);
  #pragma unroll
  for (int r = 0; r < 4; ++r) {
    const int c = quad * 4 + r;
    if (c < NC) {
      dst[(bm0 + l15) * NC + c] = acc0[r];
      dst[(bm1 + l15) * NC + c] = acc1[r];
    }
  }
}

// ---------------------------------------------------------------------------
// reduce+finalize: out[bc] = log( sum_k part[k][bc] + eps ). Thread bc reads
// part[k][bc] -- consecutive threads hit consecutive addresses (coalesced);
// ~4 MB total, L2/L3-hot. Fixed summation order -> deterministic.
// ---------------------------------------------------------------------------
__global__ __launch_bounds__(256) void reduce_kernel(
    const float* __restrict__ part, float* __restrict__ out)
{
  const int bc = blockIdx.x * 256 + threadIdx.x;
  if (bc < NB * NC) {
    float s = 0.f;
    #pragma unroll 7
    for (int k = 0; k < NCHUNK; ++k) s += part[(size_t)k * (NB * NC) + bc];
    out[bc] = __logf(s + 1e-12f);
  }
}

extern "C" void kernel_launch(void* const* d_in, const int* in_sizes, int n_in,
                              void* d_out, int out_size, void* d_ws, size_t ws_size,
                              hipStream_t stream)
{
  const float* x        = (const float*)d_in[0];
  const float* ex       = (const float*)d_in[1];
  const int*   labels   = (const int*)d_in[2];
  const float* beta_raw = (const float*)d_in[3];
  float* out = (float*)d_out;

  // Workspace layout (~10.97 MB total):
  char* ws = (char*)d_ws;
  _Float16* ex_h    = (_Float16*)ws;             // 50176*64*2 = 6,422,528 B
  float*    ce      = (float*)(ws + 6422528);    //   200,704 B
  _Float16* x_h     = (_Float16*)(ws + 6623232); //   131,072 B
  float*    cb      = (float*)(ws + 6754304);    //     4,096 B
  int*      lab_pad = (int*)(ws + 6758400);      //   200,704 B
  float*    part    = (float*)(ws + 6959104);    // 98*10240*4 = 4,014,080 B (end: 10,973,184)

  prep_kernel<<<3200, 256, 0, stream>>>(x, ex, labels, beta_raw,
                                        ex_h, ce, x_h, cb, lab_pad);
  dim3 g(NB / BCOLS, NCHUNK);
  main_kernel<<<g, 256, 0, stream>>>(ex_h, ce, x_h, cb, lab_pad, beta_raw, part);
  reduce_kernel<<<40, 256, 0, stream>>>(part, out);
}

// Round 2
// 94.471 us; speedup vs baseline: 1.0816x; 1.0053x over previous
//
#include <hip/hip_runtime.h>

// ExemplarNoAttention: logits[b,c] = log( sum_{e: label[e]==c} exp(-beta*d2[b,e]) + eps )
// d2[b,e] = ||x_b||^2 + ||e_e||^2 - 2<x_b,e_e>, clamped >= 0; beta = softplus(beta_raw).
//
// Round 11 (from R10 = 95.0 us):
//  FUSE prep into main. prep moved ~20 MB through HBM (13.3 MB fp32 reads +
//  6.75 MB fp16 side-table writes) that main immediately re-read (6.4 MB ex_h)
//  -- a 13 MB HBM round-trip whose only job was fp32->fp16 cvt + norm precompute.
//  main now:
//   - stage-loads ex as fp32 (64 B/thread/stage, coalesced 4 KB/wave; the 8
//     btiles of a chunk are co-scheduled x-major and share the slice in L2),
//   - folds norm (16 fma + 2 shfl_xor among the 4 lanes sharing a row) and
//     16 RTE cvts into the existing LDS write phase (hidden under vmcnt wait),
//   - builds x B-frags + cb once per block from fp32 x (32 KB/block, L3-hot),
//   - reads labels directly with the pad guard (grow < NE) in-kernel.
//  Numerics identical to the prep path (same RTE casts, same fp32 norms).
//  Removes: 1 launch + 1 serialization gap + ~13 MB HBM. Keeps R10's single-
//  barrier double-buffer, 128 batch cols/block, exp2 domain, dead-subtile skip.
// Flush stays contention-free private partial stores; reduce kernel unchanged.
// Harness floor (~45 us 268 MB poison fill + restores) untouchable.

#define NB      1024
#define NE      50000
#define NCHUNK  98       // 98 chunks * 512 e-rows (last chunk padded in-kernel)
#define KD      64
#define NC      10
#define SROWS   64       // e-rows per stage
#define NSTAGE  8        // 512 / SROWS
#define LROW    72       // padded LDS row stride in halfs (144 B)
#define BCOLS   128      // batch cols per block (2 col-groups of 64 per wave-set)

#define LOG2E   1.4426950408889634f

using half8   = __attribute__((ext_vector_type(8))) _Float16;  // 16x16x32 A/B frag (4 VGPRs)
using half4v  = __attribute__((ext_vector_type(4))) _Float16;  // 16x16x16 A/B frag (2 VGPRs)
using floatx4 = __attribute__((ext_vector_type(4))) float;

__device__ __forceinline__ float softplus_f(float x) {
  return (x > 20.f) ? x : log1pf(__expf(x));
}

__device__ __forceinline__ float exp2_hw(float x) {
#if __has_builtin(__builtin_amdgcn_exp2f)
  return __builtin_amdgcn_exp2f(x);
#else
  return exp2f(x);
#endif
}

// ---------------------------------------------------------------------------
// main: grid (8 btiles, 98 chunks), block = 4 waves, 128 batch cols per block.
// Wave w owns cols {btile*128 + w*16 .. +16} (group 0) and the same +64 (group 1).
// Per stage (64 e-rows): prefetch next stage ex fp32 global->regs; compute 4
// subtiles from LDS buf b (shared A-frags feed BOTH col-groups); then cvt+norm
// the prefetched rows and write to buf b^1; ONE barrier.
// Subtile: MFMA1 16x16x32 -> d[e][b] per group; t = min(s2*d + cb + ce, 0) in
// log2-domain; if all lanes dead (t<=-25 => fp16(p)==0) skip exp/onehot/MFMA2.
// Else p = exp2(t) fp16, acc_g = MFMA2(onehot, p_g, acc_g)  (onehot shared).
// Flush: plain coalesced stores into part[chunk] -- zero atomics/contention.
// ---------------------------------------------------------------------------
__global__ __launch_bounds__(256) void main_kernel(
    const float* __restrict__ x, const float* __restrict__ ex,
    const int* __restrict__ labels, const float* __restrict__ beta_raw,
    float* __restrict__ part)
{
  __shared__ _Float16 Ah[2][SROWS * LROW];
  __shared__ float    Ce[2][SROWS];
  __shared__ int      Lb[2][SROWS];

  const int tid  = threadIdx.x;
  const int wave = tid >> 6;
  const int lane = tid & 63;
  const int l15  = lane & 15;
  const int quad = lane >> 4;

  const int btile = blockIdx.x;
  const int chunk = blockIdx.y;
  const int e0    = chunk * 512;
  const int bm0   = btile * BCOLS + wave * 16;  // col-group 0
  const int bm1   = bm0 + 64;                   // col-group 1

  const float beta = softplus_f(beta_raw[0]);
  const float nb2  = -beta * LOG2E;             // -beta*log2(e)
  const float s2   = 2.f * beta * LOG2E;

  // ---- x B-frags + cb for both col-groups, from fp32 x, once per block ----
  // Lane (l15, quad) needs x[bm+l15][quad*8 .. +8) (bx?0) and cols +32 (bx?1).
  const float* xr0 = x + (size_t)(bm0 + l15) * KD;
  const float* xr1 = x + (size_t)(bm1 + l15) * KD;
  const float4 xa0 = *(const float4*)(xr0 + quad * 8);
  const float4 xa1 = *(const float4*)(xr0 + quad * 8 + 4);
  const float4 xa2 = *(const float4*)(xr0 + quad * 8 + 32);
  const float4 xa3 = *(const float4*)(xr0 + quad * 8 + 36);
  const float4 xb0 = *(const float4*)(xr1 + quad * 8);
  const float4 xb1 = *(const float4*)(xr1 + quad * 8 + 4);
  const float4 xb2 = *(const float4*)(xr1 + quad * 8 + 32);
  const float4 xb3 = *(const float4*)(xr1 + quad * 8 + 36);

  const half8 bx00 = { (_Float16)xa0.x, (_Float16)xa0.y, (_Float16)xa0.z, (_Float16)xa0.w,
                       (_Float16)xa1.x, (_Float16)xa1.y, (_Float16)xa1.z, (_Float16)xa1.w };
  const half8 bx01 = { (_Float16)xa2.x, (_Float16)xa2.y, (_Float16)xa2.z, (_Float16)xa2.w,
                       (_Float16)xa3.x, (_Float16)xa3.y, (_Float16)xa3.z, (_Float16)xa3.w };
  const half8 bx10 = { (_Float16)xb0.x, (_Float16)xb0.y, (_Float16)xb0.z, (_Float16)xb0.w,
                       (_Float16)xb1.x, (_Float16)xb1.y, (_Float16)xb1.z, (_Float16)xb1.w };
  const half8 bx11 = { (_Float16)xb2.x, (_Float16)xb2.y, (_Float16)xb2.z, (_Float16)xb2.w,
                       (_Float16)xb3.x, (_Float16)xb3.y, (_Float16)xb3.z, (_Float16)xb3.w };

  // row norms: lane holds 16 of 64 cols; quads of the same l15 cover all 64.
  float sx0 = xa0.x*xa0.x + xa0.y*xa0.y + xa0.z*xa0.z + xa0.w*xa0.w
            + xa1.x*xa1.x + xa1.y*xa1.y + xa1.z*xa1.z + xa1.w*xa1.w
            + xa2.x*xa2.x + xa2.y*xa2.y + xa2.z*xa2.z + xa2.w*xa2.w
            + xa3.x*xa3.x + xa3.y*xa3.y + xa3.z*xa3.z + xa3.w*xa3.w;
  float sx1 = xb0.x*xb0.x + xb0.y*xb0.y + xb0.z*xb0.z + xb0.w*xb0.w
            + xb1.x*xb1.x + xb1.y*xb1.y + xb1.z*xb1.z + xb1.w*xb1.w
            + xb2.x*xb2.x + xb2.y*xb2.y + xb2.z*xb2.z + xb2.w*xb2.w
            + xb3.x*xb3.x + xb3.y*xb3.y + xb3.z*xb3.z + xb3.w*xb3.w;
  sx0 += __shfl_xor(sx0, 16, 64);  sx0 += __shfl_xor(sx0, 32, 64);
  sx1 += __shfl_xor(sx1, 16, 64);  sx1 += __shfl_xor(sx1, 32, 64);
  const float cb0l = nb2 * sx0;
  const float cb1l = nb2 * sx1;

  // stage-load lane constants: thread t owns row (t>>2), fp32 cols [(t&3)*16..+16)
  const int srow = tid >> 2;
  const int scol = tid & 3;
  const int lofs = srow * LROW + scol * 16;

  float4 pf0, pf1, pf2, pf3;  // prefetched fp32 row slice
  int    prl;                 // prefetched label (scol==1 lanes)
  bool   pvalid;

  auto stage_load = [&](int st) {
    const int grow = e0 + st * SROWS + srow;
    pvalid = grow < NE;
    pf0 = make_float4(0.f, 0.f, 0.f, 0.f);
    pf1 = pf0; pf2 = pf0; pf3 = pf0;
    prl = 0;
    if (pvalid) {
      const float* g = ex + (size_t)grow * KD + scol * 16;
      pf0 = *(const float4*)(g);
      pf1 = *(const float4*)(g + 4);
      pf2 = *(const float4*)(g + 8);
      pf3 = *(const float4*)(g + 12);
      if (scol == 1) prl = labels[grow];
    }
  };

  auto stage_write = [&](int buf) {
    // norm: 16 squares + reduce across the 4 lanes sharing this row (scol)
    float sn = pf0.x*pf0.x + pf0.y*pf0.y + pf0.z*pf0.z + pf0.w*pf0.w
             + pf1.x*pf1.x + pf1.y*pf1.y + pf1.z*pf1.z + pf1.w*pf1.w
             + pf2.x*pf2.x + pf2.y*pf2.y + pf2.z*pf2.z + pf2.w*pf2.w
             + pf3.x*pf3.x + pf3.y*pf3.y + pf3.z*pf3.z + pf3.w*pf3.w;
    sn += __shfl_xor(sn, 1, 64);
    sn += __shfl_xor(sn, 2, 64);
    const half8 h0 = { (_Float16)pf0.x, (_Float16)pf0.y, (_Float16)pf0.z, (_Float16)pf0.w,
                       (_Float16)pf1.x, (_Float16)pf1.y, (_Float16)pf1.z, (_Float16)pf1.w };
    const half8 h1 = { (_Float16)pf2.x, (_Float16)pf2.y, (_Float16)pf2.z, (_Float16)pf2.w,
                       (_Float16)pf3.x, (_Float16)pf3.y, (_Float16)pf3.z, (_Float16)pf3.w };
    *(half8*)(&Ah[buf][lofs])     = h0;
    *(half8*)(&Ah[buf][lofs + 8]) = h1;
    if (scol == 0) Ce[buf][srow] = pvalid ? (nb2 * sn) : -1e30f;
    if (scol == 1) Lb[buf][srow] = prl;
  };

  // ---- prologue: stage 0 global -> regs -> LDS buf 0 ----
  stage_load(0);
  stage_write(0);
  __syncthreads();

  floatx4 acc0 = {0.f, 0.f, 0.f, 0.f};
  floatx4 acc1 = {0.f, 0.f, 0.f, 0.f};

  for (int st = 0; st < NSTAGE; ++st) {
    const int b = st & 1;

    // prefetch next stage into registers (vmcnt chain, independent of ds_reads)
    if (st + 1 < NSTAGE) stage_load(st + 1);

    // compute 4 subtiles of 16 e-rows from LDS buf b
    #pragma unroll
    for (int sub = 0; sub < 4; ++sub) {
      const int abase = (sub * 16 + l15) * LROW + quad * 8;
      const half8 ae0 = *(const half8*)(&Ah[b][abase]);
      const half8 ae1 = *(const half8*)(&Ah[b][abase + 32]);
      const float4 ce4 = *(const float4*)(&Ce[b][sub * 16 + quad * 4]);
      const int4   lb4 = *(const int4*)(&Lb[b][sub * 16 + quad * 4]);

      floatx4 d0 = {0.f, 0.f, 0.f, 0.f};
      floatx4 d1 = {0.f, 0.f, 0.f, 0.f};
      d0 = __builtin_amdgcn_mfma_f32_16x16x32_f16(ae0, bx00, d0, 0, 0, 0);
      d0 = __builtin_amdgcn_mfma_f32_16x16x32_f16(ae1, bx01, d0, 0, 0, 0);
      d1 = __builtin_amdgcn_mfma_f32_16x16x32_f16(ae0, bx10, d1, 0, 0, 0);
      d1 = __builtin_amdgcn_mfma_f32_16x16x32_f16(ae1, bx11, d1, 0, 0, 0);

      const float cef[4] = { ce4.x, ce4.y, ce4.z, ce4.w };
      float t0[4], t1[4];
      #pragma unroll
      for (int r = 0; r < 4; ++r) {
        t0[r] = fminf(fmaf(s2, d0[r], cb0l + cef[r]), 0.f);  // log2-domain
        t1[r] = fminf(fmaf(s2, d1[r], cb1l + cef[r]), 0.f);
      }

      // dead-subtile skip: t <= -25 => fp16(2^t) == 0 exactly (RTE), so the
      // MFMA2 contribution is a provable no-op. Wave-uniform branch.
      const float m0 = fmaxf(fmaxf(t0[0], t0[1]), fmaxf(t0[2], t0[3]));
      const float m1 = fmaxf(fmaxf(t1[0], t1[1]), fmaxf(t1[2], t1[3]));
      if (__any(fmaxf(m0, m1) > -25.f)) {
        half4v oh;
        oh[0] = (lb4.x == l15) ? (_Float16)1.f : (_Float16)0.f;
        oh[1] = (lb4.y == l15) ? (_Float16)1.f : (_Float16)0.f;
        oh[2] = (lb4.z == l15) ? (_Float16)1.f : (_Float16)0.f;
        oh[3] = (lb4.w == l15) ? (_Float16)1.f : (_Float16)0.f;

        half4v p0, p1;
        #pragma unroll
        for (int r = 0; r < 4; ++r) {
          p0[r] = (_Float16)exp2_hw(t0[r]);
          p1[r] = (_Float16)exp2_hw(t1[r]);
        }

        acc0 = __builtin_amdgcn_mfma_f32_16x16x16f16(oh, p0, acc0, 0, 0, 0);
        acc1 = __builtin_amdgcn_mfma_f32_16x16x16f16(oh, p1, acc1, 0, 0, 0);
      }
    }

    // single barrier per stage: writes go to buf b^1, whose last reads ended
    // before the barrier at the end of stage st-1; reads of buf b don't alias.
    if (st + 1 < NSTAGE) {
      stage_write((st + 1) & 1);
      __syncthreads();
    }
  }

  // Flush: acc holds class_part[c = quad*4+r][b = l15] per col-group. Private
  // per-chunk slice, plain stores, zero contention (each cell written once).
  float* dst = part + (size_t)chunk * (NB * NC);
  #pragma unroll
  for (int r = 0; r < 4; ++r) {
    const int c = quad * 4 + r;
    if (c < NC) {
      dst[(bm0 + l15) * NC + c] = acc0[r];
      dst[(bm1 + l15) * NC + c] = acc1[r];
    }
  }
}

// ---------------------------------------------------------------------------
// reduce+finalize: out[bc] = log( sum_k part[k][bc] + eps ). Thread bc reads
// part[k][bc] -- consecutive threads hit consecutive addresses (coalesced);
// ~4 MB total, L2/L3-hot. Fixed summation order -> deterministic.
// ---------------------------------------------------------------------------
__global__ __launch_bounds__(256) void reduce_kernel(
    const float* __restrict__ part, float* __restrict__ out)
{
  const int bc = blockIdx.x * 256 + threadIdx.x;
  if (bc < NB * NC) {
    float s = 0.f;
    #pragma unroll 7
    for (int k = 0; k < NCHUNK; ++k) s += part[(size_t)k * (NB * NC) + bc];
    out[bc] = __logf(s + 1e-12f);
  }
}

extern "C" void kernel_launch(void* const* d_in, const int* in_sizes, int n_in,
                              void* d_out, int out_size, void* d_ws, size_t ws_size,
                              hipStream_t stream)
{
  const float* x        = (const float*)d_in[0];
  const float* ex       = (const float*)d_in[1];
  const int*   labels   = (const int*)d_in[2];
  const float* beta_raw = (const float*)d_in[3];
  float* out = (float*)d_out;

  // Workspace: only the contention-free partial array (98*10240*4 = 4,014,080 B)
  float* part = (float*)d_ws;

  dim3 g(NB / BCOLS, NCHUNK);
  main_kernel<<<g, 256, 0, stream>>>(x, ex, labels, beta_raw, part);
  reduce_kernel<<<40, 256, 0, stream>>>(part, out);
}